// Round 1
// baseline (1038.686 us; speedup 1.0000x reference)
//
#include <hip/hip_runtime.h>

#define FEAT 1024
#define EPS 1e-5f

// ws layout (floats):
//   [0*F .. 5*F)  : atomic accumulators  sum_r, sum_i, sum_rr, sum_ii, sum_ri
//   [5*F .. 11*F) : fused constants      A_rr, A_ri, A_ir, A_ii, B_r, B_i

// ---------------------------------------------------------------------------
// Kernel 1: per-feature raw-moment sums. Block = 256 threads, thread t owns
// features 4t..4t+3 (float4). Grid-stride over rows; 20 atomicAdds per thread
// at the end. Memory-bound: reads 512 MiB.
// ---------------------------------------------------------------------------
__global__ __launch_bounds__(256) void stats_kernel(const float* __restrict__ real,
                                                    const float* __restrict__ imag,
                                                    float* __restrict__ ws,
                                                    int nrows) {
    const int f4 = threadIdx.x * 4;
    float sr[4]  = {0.f, 0.f, 0.f, 0.f};
    float si[4]  = {0.f, 0.f, 0.f, 0.f};
    float srr[4] = {0.f, 0.f, 0.f, 0.f};
    float sii[4] = {0.f, 0.f, 0.f, 0.f};
    float sri[4] = {0.f, 0.f, 0.f, 0.f};

    for (int row = blockIdx.x; row < nrows; row += gridDim.x) {
        const size_t off = (size_t)row * FEAT + f4;
        const float4 r  = *(const float4*)(real + off);
        const float4 im = *(const float4*)(imag + off);
        const float rv[4]  = {r.x, r.y, r.z, r.w};
        const float iv[4]  = {im.x, im.y, im.z, im.w};
#pragma unroll
        for (int k = 0; k < 4; ++k) {
            sr[k]  += rv[k];
            si[k]  += iv[k];
            srr[k] = fmaf(rv[k], rv[k], srr[k]);
            sii[k] = fmaf(iv[k], iv[k], sii[k]);
            sri[k] = fmaf(rv[k], iv[k], sri[k]);
        }
    }

#pragma unroll
    for (int k = 0; k < 4; ++k) {
        atomicAdd(&ws[0 * FEAT + f4 + k], sr[k]);
        atomicAdd(&ws[1 * FEAT + f4 + k], si[k]);
        atomicAdd(&ws[2 * FEAT + f4 + k], srr[k]);
        atomicAdd(&ws[3 * FEAT + f4 + k], sii[k]);
        atomicAdd(&ws[4 * FEAT + f4 + k], sri[k]);
    }
}

// ---------------------------------------------------------------------------
// Kernel 2: finalize — 1024 threads, one per feature. Computes the 2x2
// inverse-sqrt whitening, folds in gamma/beta/means into 6 constants.
// ---------------------------------------------------------------------------
__global__ __launch_bounds__(256) void finalize_kernel(const float* __restrict__ g_rr_p,
                                                       const float* __restrict__ g_ri_p,
                                                       const float* __restrict__ g_ii_p,
                                                       const float* __restrict__ b_r_p,
                                                       const float* __restrict__ b_i_p,
                                                       float* __restrict__ ws,
                                                       float inv_n) {
    const int f = blockIdx.x * blockDim.x + threadIdx.x;
    if (f >= FEAT) return;

    const float mr = ws[0 * FEAT + f] * inv_n;
    const float mi = ws[1 * FEAT + f] * inv_n;
    const float Crr = ws[2 * FEAT + f] * inv_n - mr * mr + EPS;
    const float Cii = ws[3 * FEAT + f] * inv_n - mi * mi + EPS;
    const float Cri = ws[4 * FEAT + f] * inv_n - mr * mi;

    const float s  = sqrtf(Crr * Cii - Cri * Cri);
    const float tt = sqrtf(Crr + Cii + 2.0f * s);
    const float inv_denom = 1.0f / (s * tt);
    const float Wrr = (Cii + s) * inv_denom;
    const float Wii = (Crr + s) * inv_denom;
    const float Wri = -Cri * inv_denom;

    const float grr = g_rr_p[f], gri = g_ri_p[f], gii = g_ii_p[f];
    const float Arr = grr * Wrr + gri * Wri;
    const float Ari = grr * Wri + gri * Wii;
    const float Air = gri * Wrr + gii * Wri;
    const float Aii = gri * Wri + gii * Wii;
    const float Br  = b_r_p[f] - Arr * mr - Ari * mi;
    const float Bi  = b_i_p[f] - Air * mr - Aii * mi;

    ws[5 * FEAT + f]  = Arr;
    ws[6 * FEAT + f]  = Ari;
    ws[7 * FEAT + f]  = Air;
    ws[8 * FEAT + f]  = Aii;
    ws[9 * FEAT + f]  = Br;
    ws[10 * FEAT + f] = Bi;
}

// ---------------------------------------------------------------------------
// Kernel 3: apply — thread t owns features 4t..4t+3; loads its 6 constant
// float4s ONCE, then grid-strides over rows. Per row: 32 B in, 32 B out,
// 16 FMA. Memory-bound: 1 GiB of traffic.
// ---------------------------------------------------------------------------
__global__ __launch_bounds__(256) void apply_kernel(const float* __restrict__ real,
                                                    const float* __restrict__ imag,
                                                    const float* __restrict__ ws,
                                                    float* __restrict__ out,
                                                    int nrows) {
    const int f4 = threadIdx.x * 4;
    const float4 Arr = *(const float4*)(ws + 5 * FEAT + f4);
    const float4 Ari = *(const float4*)(ws + 6 * FEAT + f4);
    const float4 Air = *(const float4*)(ws + 7 * FEAT + f4);
    const float4 Aii = *(const float4*)(ws + 8 * FEAT + f4);
    const float4 Br  = *(const float4*)(ws + 9 * FEAT + f4);
    const float4 Bi  = *(const float4*)(ws + 10 * FEAT + f4);

    float* __restrict__ out_i = out + (size_t)nrows * FEAT;

    for (int row = blockIdx.x; row < nrows; row += gridDim.x) {
        const size_t off = (size_t)row * FEAT + f4;
        const float4 r  = *(const float4*)(real + off);
        const float4 im = *(const float4*)(imag + off);

        float4 o_r, o_i;
        o_r.x = fmaf(Arr.x, r.x, fmaf(Ari.x, im.x, Br.x));
        o_r.y = fmaf(Arr.y, r.y, fmaf(Ari.y, im.y, Br.y));
        o_r.z = fmaf(Arr.z, r.z, fmaf(Ari.z, im.z, Br.z));
        o_r.w = fmaf(Arr.w, r.w, fmaf(Ari.w, im.w, Br.w));
        o_i.x = fmaf(Air.x, r.x, fmaf(Aii.x, im.x, Bi.x));
        o_i.y = fmaf(Air.y, r.y, fmaf(Aii.y, im.y, Bi.y));
        o_i.z = fmaf(Air.z, r.z, fmaf(Aii.z, im.z, Bi.z));
        o_i.w = fmaf(Air.w, r.w, fmaf(Aii.w, im.w, Bi.w));

        *(float4*)(out + off)   = o_r;
        *(float4*)(out_i + off) = o_i;
    }
}

extern "C" void kernel_launch(void* const* d_in, const int* in_sizes, int n_in,
                              void* d_out, int out_size, void* d_ws, size_t ws_size,
                              hipStream_t stream) {
    const float* real = (const float*)d_in[0];
    const float* imag = (const float*)d_in[1];
    const float* g_rr = (const float*)d_in[2];
    const float* g_ri = (const float*)d_in[3];
    const float* g_ii = (const float*)d_in[4];
    const float* b_r  = (const float*)d_in[5];
    const float* b_i  = (const float*)d_in[6];
    float* out = (float*)d_out;
    float* ws  = (float*)d_ws;

    const int nrows = in_sizes[0] / FEAT;  // 65536

    // Zero the 5*F atomic accumulators (ws is poisoned 0xAA before each call).
    hipMemsetAsync(ws, 0, 5 * FEAT * sizeof(float), stream);

    // Pass 1: stats. 1024 blocks (4/CU), 64 rows each.
    stats_kernel<<<1024, 256, 0, stream>>>(real, imag, ws, nrows);

    // Pass 2: finalize 1024 features.
    finalize_kernel<<<4, 256, 0, stream>>>(g_rr, g_ri, g_ii, b_r, b_i, ws,
                                           1.0f / (float)nrows);

    // Pass 3: apply. 2048 blocks (8/CU resident), 32 rows each.
    apply_kernel<<<2048, 256, 0, stream>>>(real, imag, ws, out, nrows);
}